// Round 12
// baseline (1639.674 us; speedup 1.0000x reference)
//
#include <hip/hip_runtime.h>
#include <hip/hip_bf16.h>

#define D 64
#define TSTEPS 4

__device__ __forceinline__ float selu_f(float x) {
  const float sc = 1.0507009873554805f;
  const float scal = 1.7580993408473766f;  // sc * alpha
  return x > 0.f ? sc * x : scal * (__expf(x) - 1.f);
}
__device__ __forceinline__ float sigm_f(float x) {
  return 1.f / (1.f + __expf(-x));
}
__device__ __forceinline__ float tanh_f(float x) {
  return 1.f - 2.f / (__expf(2.f * x) + 1.f);
}
__device__ __forceinline__ unsigned short f2bf(float x) {
  union { float f; unsigned u; } v; v.f = x;
  unsigned r = v.u + 0x7fff + ((v.u >> 16) & 1);  // RNE
  return (unsigned short)(r >> 16);
}
__device__ __forceinline__ float bf2f(unsigned short x) {
  union { unsigned u; float f; } v; v.u = ((unsigned)x) << 16;
  return v.f;
}

__global__ void k_hist(const int* __restrict__ sec, int* counts, int P) {
  int i = blockIdx.x * blockDim.x + threadIdx.x;
  if (i < P) atomicAdd(&counts[sec[i]], 1);
}

// ---- parallel 3-pass exclusive scan over counts[E] ----
__global__ __launch_bounds__(256) void k_scan1(const int* __restrict__ counts,
                                               int* __restrict__ bsums, int E) {
  __shared__ int red[256];
  int b = blockIdx.x, t = threadIdx.x;
  int i0 = b * 1024 + t * 4;
  int s = 0;
  if (i0 + 3 < E) {
    int4 v = *reinterpret_cast<const int4*>(counts + i0);
    s = v.x + v.y + v.z + v.w;
  } else {
#pragma unroll
    for (int j = 0; j < 4; ++j) { int i = i0 + j; if (i < E) s += counts[i]; }
  }
  red[t] = s;
  __syncthreads();
  for (int d = 128; d > 0; d >>= 1) {
    if (t < d) red[t] += red[t + d];
    __syncthreads();
  }
  if (t == 0) bsums[b] = red[0];
}

__global__ __launch_bounds__(1024) void k_scan2(int* __restrict__ bsums, int NB) {
  __shared__ int lds[1024];
  int t = threadIdx.x;
  lds[t] = (t < NB) ? bsums[t] : 0;
  __syncthreads();
  for (int d = 1; d < 1024; d <<= 1) {
    int u = (t >= d) ? lds[t - d] : 0;
    __syncthreads();
    lds[t] += u;
    __syncthreads();
  }
  if (t < NB) bsums[t] = (t == 0) ? 0 : lds[t - 1];
}

// (cursor may alias counts: each slot is read by the same thread before write)
__global__ __launch_bounds__(256) void k_scan3(const int* __restrict__ counts,
                                               const int* __restrict__ bsums,
                                               int* __restrict__ offsets,
                                               int* __restrict__ cursor, int E, int P) {
  __shared__ int red[256];
  int b = blockIdx.x, t = threadIdx.x;
  int i0 = b * 1024 + t * 4;
  int c[4];
  int s = 0;
#pragma unroll
  for (int j = 0; j < 4; ++j) {
    int i = i0 + j;
    c[j] = (i < E) ? counts[i] : 0;
    s += c[j];
  }
  red[t] = s;
  __syncthreads();
  for (int d = 1; d < 256; d <<= 1) {
    int u = (t >= d) ? red[t - d] : 0;
    __syncthreads();
    red[t] += u;
    __syncthreads();
  }
  int base = bsums[b] + ((t == 0) ? 0 : red[t - 1]);
#pragma unroll
  for (int j = 0; j < 4; ++j) {
    int i = i0 + j;
    if (i < E) {
      offsets[i] = base;
      cursor[i] = base;
      base += c[j];
    }
  }
  if (b == 0 && t == 0) offsets[E] = P;
}

__global__ void k_scatter(const int* __restrict__ fst, const int* __restrict__ sec,
                          int* cursor, int* __restrict__ sorted_first, int P) {
  int i = blockIdx.x * blockDim.x + threadIdx.x;
  if (i < P) {
    int e = sec[i];
    int pos = atomicAdd(&cursor[e], 1);
    sorted_first[pos] = fst[i];
  }
}

// build Wuv [64][128] = [W_top | W_bot], Wg [128][256], bg [256]
__global__ void k_prep(const float* __restrict__ Wmsg,
                       const float* __restrict__ gk, const float* __restrict__ grk,
                       const float* __restrict__ gb,
                       float* __restrict__ Wuv, float* __restrict__ Wg, float* __restrict__ bg) {
  int i = blockIdx.x * blockDim.x + threadIdx.x;
  if (i < 64 * 128) {
    int k = i >> 7, c = i & 127;
    Wuv[i] = (c < 64) ? Wmsg[k * 64 + c] : Wmsg[(64 + k) * 64 + (c - 64)];
  }
  if (i < 128 * 256) {
    int r = i >> 8, c = i & 255;
    float v;
    if (r < 64) {
      v = (c < 192) ? gk[r * 192 + c] : 0.f;
    } else {
      int rr = r - 64;
      if (c < 128) v = grk[rr * 192 + c];
      else if (c < 192) v = 0.f;
      else v = grk[rr * 192 + (c - 64)];
    }
    Wg[i] = v;
  }
  if (i < 256) {
    float v;
    if (i < 128) v = gb[i] + gb[192 + i];
    else if (i < 192) v = gb[i];
    else v = gb[i + 128];
    bg[i] = v;
  }
}

// UV = h @ [W_top|W_bot] (V part gets +b_msg), bf16 out -- once on initial link_state
__global__ __launch_bounds__(256) void k_uv(const float* __restrict__ h,
                                            const float* __restrict__ Wuv,
                                            const float* __restrict__ bmsg,
                                            unsigned short* __restrict__ UVp, int E) {
  __shared__ float As[32 * 65];
  int t = threadIdx.x;
  int base = blockIdx.x * 32;
  for (int q = t; q < 32 * 16; q += 256) {
    int row = q >> 4, k4 = (q & 15) << 2;
    float4 v = make_float4(0.f, 0.f, 0.f, 0.f);
    if (base + row < E)
      v = *reinterpret_cast<const float4*>(h + (size_t)(base + row) * 64 + k4);
    As[row * 65 + k4 + 0] = v.x;
    As[row * 65 + k4 + 1] = v.y;
    As[row * 65 + k4 + 2] = v.z;
    As[row * 65 + k4 + 3] = v.w;
  }
  __syncthreads();
  int ct = t & 31, eg = t >> 5;
  int c0 = ct * 4;
  float4 binit = make_float4(0.f, 0.f, 0.f, 0.f);
  if (c0 >= 64) binit = *reinterpret_cast<const float4*>(bmsg + (c0 - 64));
  float4 acc[4];
  acc[0] = binit; acc[1] = binit; acc[2] = binit; acc[3] = binit;
#pragma unroll 8
  for (int k = 0; k < 64; ++k) {
    float4 bv = *reinterpret_cast<const float4*>(Wuv + k * 128 + c0);
#pragma unroll
    for (int j = 0; j < 4; ++j) {
      float a = As[(eg + j * 8) * 65 + k];
      acc[j].x += a * bv.x; acc[j].y += a * bv.y;
      acc[j].z += a * bv.z; acc[j].w += a * bv.w;
    }
  }
#pragma unroll
  for (int j = 0; j < 4; ++j) {
    int e = base + eg + j * 8;
    if (e < E) {
      ushort4 s;
      s.x = f2bf(acc[j].x); s.y = f2bf(acc[j].y);
      s.z = f2bf(acc[j].z); s.w = f2bf(acc[j].w);
      *reinterpret_cast<ushort4*>(UVp + (size_t)e * 128 + c0) = s;
    }
  }
}

// ---- FALLBACK PATH (ws-tight): separate pair + gru, bf16 agg ----
__global__ __launch_bounds__(256) void k_pair(const unsigned short* __restrict__ UVp,
                                              const int* __restrict__ offsets,
                                              const int* __restrict__ sorted_first,
                                              unsigned short* __restrict__ aggp, int E) {
  int w = (blockIdx.x << 2) + (threadIdx.x >> 6);
  if (w >= E) return;
  int c = threadIdx.x & 63;
  float base = bf2f(UVp[(size_t)w * 128 + 64 + c]);
  int i = __builtin_amdgcn_readfirstlane(offsets[w]);
  int end = __builtin_amdgcn_readfirstlane(offsets[w + 1]);
  float acc = 0.f;
  for (; i + 3 < end; i += 4) {
    int f0 = __builtin_amdgcn_readfirstlane(sorted_first[i]);
    int f1 = __builtin_amdgcn_readfirstlane(sorted_first[i + 1]);
    int f2 = __builtin_amdgcn_readfirstlane(sorted_first[i + 2]);
    int f3 = __builtin_amdgcn_readfirstlane(sorted_first[i + 3]);
    acc += selu_f(bf2f(UVp[(size_t)f0 * 128 + c]) + base);
    acc += selu_f(bf2f(UVp[(size_t)f1 * 128 + c]) + base);
    acc += selu_f(bf2f(UVp[(size_t)f2 * 128 + c]) + base);
    acc += selu_f(bf2f(UVp[(size_t)f3 * 128 + c]) + base);
  }
  for (; i < end; ++i) {
    int f0 = __builtin_amdgcn_readfirstlane(sorted_first[i]);
    acc += selu_f(bf2f(UVp[(size_t)f0 * 128 + c]) + base);
  }
  aggp[(size_t)w * 64 + c] = f2bf(acc);
}

__global__ __launch_bounds__(256) void k_gru(const unsigned short* __restrict__ aggp,
                                             const float* __restrict__ h_in,
                                             float* __restrict__ h_out,
                                             const float* __restrict__ Wg,
                                             const float* __restrict__ bg,
                                             const float* __restrict__ Wuv,
                                             const float* __restrict__ bmsg,
                                             unsigned short* __restrict__ UVp,
                                             float* __restrict__ g,
                                             int E, int write_uv, int accum_g) {
  __shared__ float As[32 * 129];
  __shared__ float Ms[32 * 257];
  __shared__ float red[256];
  int t = threadIdx.x;
  int base = blockIdx.x * 32;

  for (int q = t; q < 32 * 32; q += 256) {
    int row = q >> 5, c4 = (q & 31) << 2;
    int e = base + row;
    float4 v = make_float4(0.f, 0.f, 0.f, 0.f);
    if (e < E) {
      if (c4 < 64) {
        ushort4 s = *reinterpret_cast<const ushort4*>(aggp + (size_t)e * 64 + c4);
        v = make_float4(bf2f(s.x), bf2f(s.y), bf2f(s.z), bf2f(s.w));
      } else {
        v = *reinterpret_cast<const float4*>(h_in + (size_t)e * 64 + (c4 - 64));
      }
    }
    As[row * 129 + c4 + 0] = v.x;
    As[row * 129 + c4 + 1] = v.y;
    As[row * 129 + c4 + 2] = v.z;
    As[row * 129 + c4 + 3] = v.w;
  }
  __syncthreads();

  {
    int wv = t >> 6;
    int lane = t & 63;
    int ct8 = lane & 7;
    int rg = lane >> 3;
    int c0 = wv * 64 + ct8 * 8;
    int kbeg = (wv == 3) ? 64 : 0;
    int kend = (wv == 2) ? 64 : 128;
    float4 b0 = *reinterpret_cast<const float4*>(bg + c0);
    float4 b1 = *reinterpret_cast<const float4*>(bg + c0 + 4);
    float4 acc0[4], acc1[4];
#pragma unroll
    for (int j = 0; j < 4; ++j) { acc0[j] = b0; acc1[j] = b1; }
#pragma unroll 4
    for (int k = kbeg; k < kend; ++k) {
      float4 bv0 = *reinterpret_cast<const float4*>(Wg + k * 256 + c0);
      float4 bv1 = *reinterpret_cast<const float4*>(Wg + k * 256 + c0 + 4);
#pragma unroll
      for (int j = 0; j < 4; ++j) {
        float a = As[(rg + j * 8) * 129 + k];
        acc0[j].x += a * bv0.x; acc0[j].y += a * bv0.y;
        acc0[j].z += a * bv0.z; acc0[j].w += a * bv0.w;
        acc1[j].x += a * bv1.x; acc1[j].y += a * bv1.y;
        acc1[j].z += a * bv1.z; acc1[j].w += a * bv1.w;
      }
    }
#pragma unroll
    for (int j = 0; j < 4; ++j) {
      float* m = Ms + (rg + j * 8) * 257 + c0;
      m[0] = acc0[j].x; m[1] = acc0[j].y; m[2] = acc0[j].z; m[3] = acc0[j].w;
      m[4] = acc1[j].x; m[5] = acc1[j].y; m[6] = acc1[j].z; m[7] = acc1[j].w;
    }
  }
  __syncthreads();

  float gsum = 0.f;
#pragma unroll
  for (int j = 0; j < 8; ++j) {
    int u = t + 256 * j;
    int e = u >> 6, c = u & 63;
    int ge = base + e;
    float mz = Ms[e * 257 + c];
    float mr = Ms[e * 257 + 64 + c];
    float mx2 = Ms[e * 257 + 128 + c];
    float mi2 = Ms[e * 257 + 192 + c];
    float hold = As[e * 129 + 64 + c];
    float z = sigm_f(mz);
    float r = sigm_f(mr);
    float hh = tanh_f(mx2 + r * mi2);
    float hn = z * hold + (1.f - z) * hh;
    if (ge < E) {
      if (!accum_g) h_out[(size_t)ge * 64 + c] = hn;
    } else {
      hn = 0.f;
    }
    As[e * 129 + 64 + c] = hn;
    gsum += hn;
  }
  __syncthreads();

  if (write_uv) {
    int ct = t & 31, eg = t >> 5;
    int c0 = ct * 4;
    float4 binit = make_float4(0.f, 0.f, 0.f, 0.f);
    if (c0 >= 64) binit = *reinterpret_cast<const float4*>(bmsg + (c0 - 64));
    float4 acc[4];
    acc[0] = binit; acc[1] = binit; acc[2] = binit; acc[3] = binit;
#pragma unroll 8
    for (int k = 0; k < 64; ++k) {
      float4 bv = *reinterpret_cast<const float4*>(Wuv + k * 128 + c0);
#pragma unroll
      for (int j = 0; j < 4; ++j) {
        float a = As[(eg + j * 8) * 129 + 64 + k];
        acc[j].x += a * bv.x; acc[j].y += a * bv.y;
        acc[j].z += a * bv.z; acc[j].w += a * bv.w;
      }
    }
#pragma unroll
    for (int j = 0; j < 4; ++j) {
      int e = base + eg + j * 8;
      if (e < E) {
        ushort4 s;
        s.x = f2bf(acc[j].x); s.y = f2bf(acc[j].y);
        s.z = f2bf(acc[j].z); s.w = f2bf(acc[j].w);
        *reinterpret_cast<ushort4*>(UVp + (size_t)e * 128 + c0) = s;
      }
    }
  }

  if (accum_g) {
    red[t] = gsum;
    __syncthreads();
    if (t < 64) atomicAdd(&g[t], red[t] + red[t + 64] + red[t + 128] + red[t + 192]);
  }
}

// ---- FUSED PATH: pair-agg + GRU + UV-out in one kernel (UV ping-pong) ----
// Reads UVin (prev iter), writes UVout (next iter) -- race-free across blocks.
__global__ __launch_bounds__(256) void k_fused(const unsigned short* __restrict__ UVin,
                                               const int* __restrict__ offsets,
                                               const int* __restrict__ sorted_first,
                                               const float* __restrict__ h_in,
                                               float* __restrict__ h_out,
                                               const float* __restrict__ Wg,
                                               const float* __restrict__ bg,
                                               const float* __restrict__ Wuv,
                                               const float* __restrict__ bmsg,
                                               unsigned short* __restrict__ UVout,
                                               float* __restrict__ g,
                                               int E, int write_uv, int accum_g) {
  __shared__ float As[32 * 129];   // [agg | h]; h slot later holds h_new
  __shared__ float Ms[32 * 257];
  __shared__ float red[256];
  int t = threadIdx.x;
  int base = blockIdx.x * 32;

  // ---- phase 0: stage h_in into As[.][64..127] (write-only, no sync needed yet)
  for (int q = t; q < 32 * 16; q += 256) {
    int row = q >> 4, c4 = (q & 15) << 2;
    int e = base + row;
    float4 v = make_float4(0.f, 0.f, 0.f, 0.f);
    if (e < E) v = *reinterpret_cast<const float4*>(h_in + (size_t)e * 64 + c4);
    As[row * 129 + 64 + c4 + 0] = v.x;
    As[row * 129 + 64 + c4 + 1] = v.y;
    As[row * 129 + 64 + c4 + 2] = v.z;
    As[row * 129 + 64 + c4 + 3] = v.w;
  }

  // ---- phase 1: pair aggregation -> As[.][0..63]. Wave wv: edges wv*8+j.
  {
    int wv = t >> 6, c = t & 63;
    for (int j = 0; j < 8; ++j) {
      int row = wv * 8 + j;
      int e = base + row;
      float acc = 0.f;
      if (e < E) {
        float vb = bf2f(UVin[(size_t)e * 128 + 64 + c]);
        int i = __builtin_amdgcn_readfirstlane(offsets[e]);
        int end = __builtin_amdgcn_readfirstlane(offsets[e + 1]);
        for (; i + 3 < end; i += 4) {
          int f0 = __builtin_amdgcn_readfirstlane(sorted_first[i]);
          int f1 = __builtin_amdgcn_readfirstlane(sorted_first[i + 1]);
          int f2 = __builtin_amdgcn_readfirstlane(sorted_first[i + 2]);
          int f3 = __builtin_amdgcn_readfirstlane(sorted_first[i + 3]);
          acc += selu_f(bf2f(UVin[(size_t)f0 * 128 + c]) + vb);
          acc += selu_f(bf2f(UVin[(size_t)f1 * 128 + c]) + vb);
          acc += selu_f(bf2f(UVin[(size_t)f2 * 128 + c]) + vb);
          acc += selu_f(bf2f(UVin[(size_t)f3 * 128 + c]) + vb);
        }
        for (; i < end; ++i) {
          int f0 = __builtin_amdgcn_readfirstlane(sorted_first[i]);
          acc += selu_f(bf2f(UVin[(size_t)f0 * 128 + c]) + vb);
        }
      }
      As[row * 129 + c] = acc;
    }
  }
  __syncthreads();

  // ---- phase 2: M = As @ Wg (zero-block skip; wave wv owns cols [wv*64, +64))
  {
    int wv = t >> 6;
    int lane = t & 63;
    int ct8 = lane & 7;
    int rg = lane >> 3;
    int c0 = wv * 64 + ct8 * 8;
    int kbeg = (wv == 3) ? 64 : 0;
    int kend = (wv == 2) ? 64 : 128;
    float4 b0 = *reinterpret_cast<const float4*>(bg + c0);
    float4 b1 = *reinterpret_cast<const float4*>(bg + c0 + 4);
    float4 acc0[4], acc1[4];
#pragma unroll
    for (int j = 0; j < 4; ++j) { acc0[j] = b0; acc1[j] = b1; }
#pragma unroll 4
    for (int k = kbeg; k < kend; ++k) {
      float4 bv0 = *reinterpret_cast<const float4*>(Wg + k * 256 + c0);
      float4 bv1 = *reinterpret_cast<const float4*>(Wg + k * 256 + c0 + 4);
#pragma unroll
      for (int j = 0; j < 4; ++j) {
        float a = As[(rg + j * 8) * 129 + k];
        acc0[j].x += a * bv0.x; acc0[j].y += a * bv0.y;
        acc0[j].z += a * bv0.z; acc0[j].w += a * bv0.w;
        acc1[j].x += a * bv1.x; acc1[j].y += a * bv1.y;
        acc1[j].z += a * bv1.z; acc1[j].w += a * bv1.w;
      }
    }
#pragma unroll
    for (int j = 0; j < 4; ++j) {
      float* m = Ms + (rg + j * 8) * 257 + c0;
      m[0] = acc0[j].x; m[1] = acc0[j].y; m[2] = acc0[j].z; m[3] = acc0[j].w;
      m[4] = acc1[j].x; m[5] = acc1[j].y; m[6] = acc1[j].z; m[7] = acc1[j].w;
    }
  }
  __syncthreads();

  // ---- phase 3: gate epilogue; h_new -> global (skip on last iter) + As h-slot
  float gsum = 0.f;
#pragma unroll
  for (int j = 0; j < 8; ++j) {
    int u = t + 256 * j;
    int e = u >> 6, c = u & 63;
    int ge = base + e;
    float mz = Ms[e * 257 + c];
    float mr = Ms[e * 257 + 64 + c];
    float mx2 = Ms[e * 257 + 128 + c];
    float mi2 = Ms[e * 257 + 192 + c];
    float hold = As[e * 129 + 64 + c];
    float z = sigm_f(mz);
    float r = sigm_f(mr);
    float hh = tanh_f(mx2 + r * mi2);
    float hn = z * hold + (1.f - z) * hh;
    if (ge < E) {
      if (!accum_g) h_out[(size_t)ge * 64 + c] = hn;
    } else {
      hn = 0.f;
    }
    As[e * 129 + 64 + c] = hn;
    gsum += hn;
  }
  __syncthreads();

  // ---- phase 4: UVout = [h_new @ W_top | h_new @ W_bot + bmsg]
  if (write_uv) {
    int ct = t & 31, eg = t >> 5;
    int c0 = ct * 4;
    float4 binit = make_float4(0.f, 0.f, 0.f, 0.f);
    if (c0 >= 64) binit = *reinterpret_cast<const float4*>(bmsg + (c0 - 64));
    float4 acc[4];
    acc[0] = binit; acc[1] = binit; acc[2] = binit; acc[3] = binit;
#pragma unroll 8
    for (int k = 0; k < 64; ++k) {
      float4 bv = *reinterpret_cast<const float4*>(Wuv + k * 128 + c0);
#pragma unroll
      for (int j = 0; j < 4; ++j) {
        float a = As[(eg + j * 8) * 129 + 64 + k];
        acc[j].x += a * bv.x; acc[j].y += a * bv.y;
        acc[j].z += a * bv.z; acc[j].w += a * bv.w;
      }
    }
#pragma unroll
    for (int j = 0; j < 4; ++j) {
      int e = base + eg + j * 8;
      if (e < E) {
        ushort4 s;
        s.x = f2bf(acc[j].x); s.y = f2bf(acc[j].y);
        s.z = f2bf(acc[j].z); s.w = f2bf(acc[j].w);
        *reinterpret_cast<ushort4*>(UVout + (size_t)e * 128 + c0) = s;
      }
    }
  }

  // ---- phase 5: readout column-sum (last iteration only)
  if (accum_g) {
    red[t] = gsum;
    __syncthreads();
    if (t < 64) atomicAdd(&g[t], red[t] + red[t + 64] + red[t + 128] + red[t + 192]);
  }
}

__global__ __launch_bounds__(256) void k_mlp(const float* __restrict__ g,
                                             const float* __restrict__ W1, const float* __restrict__ b1,
                                             const float* __restrict__ W2, const float* __restrict__ b2,
                                             const float* __restrict__ W3, const float* __restrict__ b3,
                                             float* __restrict__ out) {
  __shared__ float gs[64];
  __shared__ float h1[256];
  __shared__ float h2[256];
  __shared__ float red[256];
  int t = threadIdx.x;
  if (t < 64) gs[t] = g[t];
  __syncthreads();
  float acc = b1[t];
#pragma unroll
  for (int k = 0; k < 64; ++k) acc += gs[k] * W1[k * 256 + t];
  h1[t] = selu_f(acc);
  __syncthreads();
  acc = b2[t];
#pragma unroll 8
  for (int k = 0; k < 256; ++k) acc += h1[k] * W2[k * 256 + t];
  h2[t] = selu_f(acc);
  __syncthreads();
  red[t] = h2[t] * W3[t];
  __syncthreads();
  for (int d = 128; d > 0; d >>= 1) {
    if (t < d) red[t] += red[t + d];
    __syncthreads();
  }
  if (t == 0) out[0] = red[0] + b3[0];
}

extern "C" void kernel_launch(void* const* d_in, const int* in_sizes, int n_in,
                              void* d_out, int out_size, void* d_ws, size_t ws_size,
                              hipStream_t stream) {
  const float* ls   = (const float*)d_in[0];
  const int*   fst  = (const int*)d_in[1];
  const int*   sec  = (const int*)d_in[2];
  const float* Wmsg = (const float*)d_in[4];
  const float* bmsg = (const float*)d_in[5];
  const float* gk   = (const float*)d_in[6];
  const float* grk  = (const float*)d_in[7];
  const float* gb   = (const float*)d_in[8];
  const float* W1   = (const float*)d_in[9];
  const float* b1   = (const float*)d_in[10];
  const float* W2   = (const float*)d_in[11];
  const float* b2   = (const float*)d_in[12];
  const float* W3   = (const float*)d_in[13];
  const float* b3   = (const float*)d_in[14];
  int E = in_sizes[0] / D;
  int P = in_sizes[1];
  float* out = (float*)d_out;
  (void)n_in; (void)out_size;

  int NB = (E + 1023) / 1024;  // scan blocks (E=100K -> 98, must be <=1024)

  // ws layout (graph-safe: depends only on ws_size):
  //  fused:    h + 2x bf16 UV (ping-pong)           ~84.2 MB
  //  fallback: h + 1x bf16 UV + bf16 agg (separate) ~71.4 MB
  auto total_need = [&](int fused) -> size_t {
    size_t o = 0;
    auto add = [&](size_t b) { o = (o + b + 255) & ~(size_t)255; };
    add((size_t)E * 64 * 4);                      // h
    add((size_t)E * 128 * 2);                     // UV0 bf16
    add(fused ? (size_t)E * 128 * 2              // UV1 bf16 (ping-pong)
              : (size_t)E * 64 * 2);             // agg bf16
    add(((size_t)E + 1) * 4);                     // offsets
    add((size_t)E * 4);                           // counts (aliased by cursor)
    add((size_t)NB * 4);                          // bsums
    add((size_t)P * 4);                           // sorted_first
    add(64 * 128 * 4);                            // Wuv
    add(128 * 256 * 4);                           // Wg
    add(256 * 4);                                 // bg
    add(64 * 4);                                  // g
    return o;
  };
  int fused = (total_need(1) <= ws_size) ? 1 : 0;

  char* ws = (char*)d_ws;
  size_t off = 0;
  auto alloc = [&](size_t bytes) {
    void* p = ws + off;
    off = (off + bytes + 255) & ~(size_t)255;
    return p;
  };
  float*          h     = (float*)alloc((size_t)E * 64 * 4);
  unsigned short* UV0   = (unsigned short*)alloc((size_t)E * 128 * 2);
  unsigned short* UV1   = nullptr;   // fused only
  unsigned short* aggb  = nullptr;   // fallback only
  if (fused) UV1  = (unsigned short*)alloc((size_t)E * 128 * 2);
  else       aggb = (unsigned short*)alloc((size_t)E * 64 * 2);
  int*   offsets      = (int*)alloc(((size_t)E + 1) * 4);
  int*   counts       = (int*)alloc((size_t)E * 4);
  int*   cursor       = counts;  // alias: scan3 reads-then-writes each slot in-thread
  int*   bsums        = (int*)alloc((size_t)NB * 4);
  int*   sorted_first = (int*)alloc((size_t)P * 4);
  float* Wuv          = (float*)alloc(64 * 128 * 4);
  float* Wg           = (float*)alloc(128 * 256 * 4);
  float* bg           = (float*)alloc(256 * 4);
  float* g            = (float*)alloc(64 * 4);

  hipMemsetAsync(counts, 0, (size_t)E * 4, stream);
  hipMemsetAsync(g, 0, 64 * 4, stream);
  k_hist<<<(P + 255) / 256, 256, 0, stream>>>(sec, counts, P);
  k_scan1<<<NB, 256, 0, stream>>>(counts, bsums, E);
  k_scan2<<<1, 1024, 0, stream>>>(bsums, NB);
  k_scan3<<<NB, 256, 0, stream>>>(counts, bsums, offsets, cursor, E, P);
  k_scatter<<<(P + 255) / 256, 256, 0, stream>>>(fst, sec, cursor, sorted_first, P);
  k_prep<<<128, 256, 0, stream>>>(Wmsg, gk, grk, gb, Wuv, Wg, bg);

  int gemm_blocks = (E + 31) / 32;
  int pair_blocks = (E + 3) / 4;

  k_uv<<<gemm_blocks, 256, 0, stream>>>(ls, Wuv, bmsg, UV0, E);
  if (fused) {
    unsigned short* UVa = UV0;
    unsigned short* UVb = UV1;
    for (int it = 0; it < TSTEPS; ++it) {
      const float* hin = (it == 0) ? ls : h;
      int last = (it == TSTEPS - 1);
      k_fused<<<gemm_blocks, 256, 0, stream>>>(UVa, offsets, sorted_first, hin, h,
                                               Wg, bg, Wuv, bmsg, UVb, g,
                                               E, !last, last);
      unsigned short* tmp = UVa; UVa = UVb; UVb = tmp;
    }
  } else {
    for (int it = 0; it < TSTEPS; ++it) {
      const float* hin = (it == 0) ? ls : h;
      int last = (it == TSTEPS - 1);
      k_pair<<<pair_blocks, 256, 0, stream>>>(UV0, offsets, sorted_first, aggb, E);
      k_gru<<<gemm_blocks, 256, 0, stream>>>(aggb, hin, h, Wg, bg, Wuv, bmsg, UV0, g,
                                             E, !last, last);
    }
  }
  k_mlp<<<1, 256, 0, stream>>>(g, W1, b1, W2, b2, W3, b3, out);
}

// Round 13
// 1189.550 us; speedup vs baseline: 1.3784x; 1.3784x over previous
//
#include <hip/hip_runtime.h>
#include <hip/hip_bf16.h>

#define D 64
#define TSTEPS 4

__device__ __forceinline__ float selu_f(float x) {
  const float sc = 1.0507009873554805f;
  const float scal = 1.7580993408473766f;  // sc * alpha
  return x > 0.f ? sc * x : scal * (__expf(x) - 1.f);
}
__device__ __forceinline__ float sigm_f(float x) {
  return 1.f / (1.f + __expf(-x));
}
__device__ __forceinline__ float tanh_f(float x) {
  return 1.f - 2.f / (__expf(2.f * x) + 1.f);
}
__device__ __forceinline__ unsigned short f2bf(float x) {
  union { float f; unsigned u; } v; v.f = x;
  unsigned r = v.u + 0x7fff + ((v.u >> 16) & 1);  // RNE
  return (unsigned short)(r >> 16);
}
__device__ __forceinline__ float bf2f(unsigned short x) {
  union { unsigned u; float f; } v; v.u = ((unsigned)x) << 16;
  return v.f;
}

__global__ void k_hist(const int* __restrict__ sec, int* counts, int P) {
  int i = blockIdx.x * blockDim.x + threadIdx.x;
  if (i < P) atomicAdd(&counts[sec[i]], 1);
}

// ---- parallel 3-pass exclusive scan over counts[E] ----
__global__ __launch_bounds__(256) void k_scan1(const int* __restrict__ counts,
                                               int* __restrict__ bsums, int E) {
  __shared__ int red[256];
  int b = blockIdx.x, t = threadIdx.x;
  int i0 = b * 1024 + t * 4;
  int s = 0;
  if (i0 + 3 < E) {
    int4 v = *reinterpret_cast<const int4*>(counts + i0);
    s = v.x + v.y + v.z + v.w;
  } else {
#pragma unroll
    for (int j = 0; j < 4; ++j) { int i = i0 + j; if (i < E) s += counts[i]; }
  }
  red[t] = s;
  __syncthreads();
  for (int d = 128; d > 0; d >>= 1) {
    if (t < d) red[t] += red[t + d];
    __syncthreads();
  }
  if (t == 0) bsums[b] = red[0];
}

__global__ __launch_bounds__(1024) void k_scan2(int* __restrict__ bsums, int NB) {
  __shared__ int lds[1024];
  int t = threadIdx.x;
  lds[t] = (t < NB) ? bsums[t] : 0;
  __syncthreads();
  for (int d = 1; d < 1024; d <<= 1) {
    int u = (t >= d) ? lds[t - d] : 0;
    __syncthreads();
    lds[t] += u;
    __syncthreads();
  }
  if (t < NB) bsums[t] = (t == 0) ? 0 : lds[t - 1];
}

// (cursor may alias counts: each slot is read by the same thread before write)
__global__ __launch_bounds__(256) void k_scan3(const int* __restrict__ counts,
                                               const int* __restrict__ bsums,
                                               int* __restrict__ offsets,
                                               int* __restrict__ cursor, int E, int P) {
  __shared__ int red[256];
  int b = blockIdx.x, t = threadIdx.x;
  int i0 = b * 1024 + t * 4;
  int c[4];
  int s = 0;
#pragma unroll
  for (int j = 0; j < 4; ++j) {
    int i = i0 + j;
    c[j] = (i < E) ? counts[i] : 0;
    s += c[j];
  }
  red[t] = s;
  __syncthreads();
  for (int d = 1; d < 256; d <<= 1) {
    int u = (t >= d) ? red[t - d] : 0;
    __syncthreads();
    red[t] += u;
    __syncthreads();
  }
  int base = bsums[b] + ((t == 0) ? 0 : red[t - 1]);
#pragma unroll
  for (int j = 0; j < 4; ++j) {
    int i = i0 + j;
    if (i < E) {
      offsets[i] = base;
      cursor[i] = base;
      base += c[j];
    }
  }
  if (b == 0 && t == 0) offsets[E] = P;
}

__global__ void k_scatter(const int* __restrict__ fst, const int* __restrict__ sec,
                          int* cursor, int* __restrict__ sorted_first, int P) {
  int i = blockIdx.x * blockDim.x + threadIdx.x;
  if (i < P) {
    int e = sec[i];
    int pos = atomicAdd(&cursor[e], 1);
    sorted_first[pos] = fst[i];
  }
}

// build Wuv [64][128] = [W_top | W_bot], Wg [128][256], bg [256]
__global__ void k_prep(const float* __restrict__ Wmsg,
                       const float* __restrict__ gk, const float* __restrict__ grk,
                       const float* __restrict__ gb,
                       float* __restrict__ Wuv, float* __restrict__ Wg, float* __restrict__ bg) {
  int i = blockIdx.x * blockDim.x + threadIdx.x;
  if (i < 64 * 128) {
    int k = i >> 7, c = i & 127;
    Wuv[i] = (c < 64) ? Wmsg[k * 64 + c] : Wmsg[(64 + k) * 64 + (c - 64)];
  }
  if (i < 128 * 256) {
    int r = i >> 8, c = i & 255;
    float v;
    if (r < 64) {
      v = (c < 192) ? gk[r * 192 + c] : 0.f;
    } else {
      int rr = r - 64;
      if (c < 128) v = grk[rr * 192 + c];
      else if (c < 192) v = 0.f;
      else v = grk[rr * 192 + (c - 64)];
    }
    Wg[i] = v;
  }
  if (i < 256) {
    float v;
    if (i < 128) v = gb[i] + gb[192 + i];
    else if (i < 192) v = gb[i];
    else v = gb[i + 128];
    bg[i] = v;
  }
}

// UV = h @ [W_top|W_bot] (V part gets +b_msg), bf16 out -- once on initial link_state
__global__ __launch_bounds__(256) void k_uv(const float* __restrict__ h,
                                            const float* __restrict__ Wuv,
                                            const float* __restrict__ bmsg,
                                            unsigned short* __restrict__ UVp, int E) {
  __shared__ float As[32 * 65];
  int t = threadIdx.x;
  int base = blockIdx.x * 32;
  for (int q = t; q < 32 * 16; q += 256) {
    int row = q >> 4, k4 = (q & 15) << 2;
    float4 v = make_float4(0.f, 0.f, 0.f, 0.f);
    if (base + row < E)
      v = *reinterpret_cast<const float4*>(h + (size_t)(base + row) * 64 + k4);
    As[row * 65 + k4 + 0] = v.x;
    As[row * 65 + k4 + 1] = v.y;
    As[row * 65 + k4 + 2] = v.z;
    As[row * 65 + k4 + 3] = v.w;
  }
  __syncthreads();
  int ct = t & 31, eg = t >> 5;
  int c0 = ct * 4;
  float4 binit = make_float4(0.f, 0.f, 0.f, 0.f);
  if (c0 >= 64) binit = *reinterpret_cast<const float4*>(bmsg + (c0 - 64));
  float4 acc[4];
  acc[0] = binit; acc[1] = binit; acc[2] = binit; acc[3] = binit;
#pragma unroll 8
  for (int k = 0; k < 64; ++k) {
    float4 bv = *reinterpret_cast<const float4*>(Wuv + k * 128 + c0);
#pragma unroll
    for (int j = 0; j < 4; ++j) {
      float a = As[(eg + j * 8) * 65 + k];
      acc[j].x += a * bv.x; acc[j].y += a * bv.y;
      acc[j].z += a * bv.z; acc[j].w += a * bv.w;
    }
  }
#pragma unroll
  for (int j = 0; j < 4; ++j) {
    int e = base + eg + j * 8;
    if (e < E) {
      ushort4 s;
      s.x = f2bf(acc[j].x); s.y = f2bf(acc[j].y);
      s.z = f2bf(acc[j].z); s.w = f2bf(acc[j].w);
      *reinterpret_cast<ushort4*>(UVp + (size_t)e * 128 + c0) = s;
    }
  }
}

// ---- FALLBACK PATH (ws-tight): separate pair + gru, bf16 agg ----
__global__ __launch_bounds__(256) void k_pair(const unsigned short* __restrict__ UVp,
                                              const int* __restrict__ offsets,
                                              const int* __restrict__ sorted_first,
                                              unsigned short* __restrict__ aggp, int E) {
  int w = (blockIdx.x << 2) + (threadIdx.x >> 6);
  if (w >= E) return;
  int c = threadIdx.x & 63;
  float base = bf2f(UVp[(size_t)w * 128 + 64 + c]);
  int i = __builtin_amdgcn_readfirstlane(offsets[w]);
  int end = __builtin_amdgcn_readfirstlane(offsets[w + 1]);
  float acc = 0.f;
  for (; i + 3 < end; i += 4) {
    int f0 = __builtin_amdgcn_readfirstlane(sorted_first[i]);
    int f1 = __builtin_amdgcn_readfirstlane(sorted_first[i + 1]);
    int f2 = __builtin_amdgcn_readfirstlane(sorted_first[i + 2]);
    int f3 = __builtin_amdgcn_readfirstlane(sorted_first[i + 3]);
    acc += selu_f(bf2f(UVp[(size_t)f0 * 128 + c]) + base);
    acc += selu_f(bf2f(UVp[(size_t)f1 * 128 + c]) + base);
    acc += selu_f(bf2f(UVp[(size_t)f2 * 128 + c]) + base);
    acc += selu_f(bf2f(UVp[(size_t)f3 * 128 + c]) + base);
  }
  for (; i < end; ++i) {
    int f0 = __builtin_amdgcn_readfirstlane(sorted_first[i]);
    acc += selu_f(bf2f(UVp[(size_t)f0 * 128 + c]) + base);
  }
  aggp[(size_t)w * 64 + c] = f2bf(acc);
}

__global__ __launch_bounds__(256) void k_gru(const unsigned short* __restrict__ aggp,
                                             const float* __restrict__ h_in,
                                             float* __restrict__ h_out,
                                             const float* __restrict__ Wg,
                                             const float* __restrict__ bg,
                                             const float* __restrict__ Wuv,
                                             const float* __restrict__ bmsg,
                                             unsigned short* __restrict__ UVp,
                                             float* __restrict__ g,
                                             int E, int write_uv, int accum_g) {
  __shared__ float As[32 * 129];
  __shared__ float Ms[32 * 257];
  __shared__ float red[256];
  int t = threadIdx.x;
  int base = blockIdx.x * 32;

  for (int q = t; q < 32 * 32; q += 256) {
    int row = q >> 5, c4 = (q & 31) << 2;
    int e = base + row;
    float4 v = make_float4(0.f, 0.f, 0.f, 0.f);
    if (e < E) {
      if (c4 < 64) {
        ushort4 s = *reinterpret_cast<const ushort4*>(aggp + (size_t)e * 64 + c4);
        v = make_float4(bf2f(s.x), bf2f(s.y), bf2f(s.z), bf2f(s.w));
      } else {
        v = *reinterpret_cast<const float4*>(h_in + (size_t)e * 64 + (c4 - 64));
      }
    }
    As[row * 129 + c4 + 0] = v.x;
    As[row * 129 + c4 + 1] = v.y;
    As[row * 129 + c4 + 2] = v.z;
    As[row * 129 + c4 + 3] = v.w;
  }
  __syncthreads();

  {
    int wv = t >> 6;
    int lane = t & 63;
    int ct8 = lane & 7;
    int rg = lane >> 3;
    int c0 = wv * 64 + ct8 * 8;
    int kbeg = (wv == 3) ? 64 : 0;
    int kend = (wv == 2) ? 64 : 128;
    float4 b0 = *reinterpret_cast<const float4*>(bg + c0);
    float4 b1 = *reinterpret_cast<const float4*>(bg + c0 + 4);
    float4 acc0[4], acc1[4];
#pragma unroll
    for (int j = 0; j < 4; ++j) { acc0[j] = b0; acc1[j] = b1; }
#pragma unroll 4
    for (int k = kbeg; k < kend; ++k) {
      float4 bv0 = *reinterpret_cast<const float4*>(Wg + k * 256 + c0);
      float4 bv1 = *reinterpret_cast<const float4*>(Wg + k * 256 + c0 + 4);
#pragma unroll
      for (int j = 0; j < 4; ++j) {
        float a = As[(rg + j * 8) * 129 + k];
        acc0[j].x += a * bv0.x; acc0[j].y += a * bv0.y;
        acc0[j].z += a * bv0.z; acc0[j].w += a * bv0.w;
        acc1[j].x += a * bv1.x; acc1[j].y += a * bv1.y;
        acc1[j].z += a * bv1.z; acc1[j].w += a * bv1.w;
      }
    }
#pragma unroll
    for (int j = 0; j < 4; ++j) {
      float* m = Ms + (rg + j * 8) * 257 + c0;
      m[0] = acc0[j].x; m[1] = acc0[j].y; m[2] = acc0[j].z; m[3] = acc0[j].w;
      m[4] = acc1[j].x; m[5] = acc1[j].y; m[6] = acc1[j].z; m[7] = acc1[j].w;
    }
  }
  __syncthreads();

  float gsum = 0.f;
#pragma unroll
  for (int j = 0; j < 8; ++j) {
    int u = t + 256 * j;
    int e = u >> 6, c = u & 63;
    int ge = base + e;
    float mz = Ms[e * 257 + c];
    float mr = Ms[e * 257 + 64 + c];
    float mx2 = Ms[e * 257 + 128 + c];
    float mi2 = Ms[e * 257 + 192 + c];
    float hold = As[e * 129 + 64 + c];
    float z = sigm_f(mz);
    float r = sigm_f(mr);
    float hh = tanh_f(mx2 + r * mi2);
    float hn = z * hold + (1.f - z) * hh;
    if (ge < E) {
      if (!accum_g) h_out[(size_t)ge * 64 + c] = hn;
    } else {
      hn = 0.f;
    }
    As[e * 129 + 64 + c] = hn;
    gsum += hn;
  }
  __syncthreads();

  if (write_uv) {
    int ct = t & 31, eg = t >> 5;
    int c0 = ct * 4;
    float4 binit = make_float4(0.f, 0.f, 0.f, 0.f);
    if (c0 >= 64) binit = *reinterpret_cast<const float4*>(bmsg + (c0 - 64));
    float4 acc[4];
    acc[0] = binit; acc[1] = binit; acc[2] = binit; acc[3] = binit;
#pragma unroll 8
    for (int k = 0; k < 64; ++k) {
      float4 bv = *reinterpret_cast<const float4*>(Wuv + k * 128 + c0);
#pragma unroll
      for (int j = 0; j < 4; ++j) {
        float a = As[(eg + j * 8) * 129 + 64 + k];
        acc[j].x += a * bv.x; acc[j].y += a * bv.y;
        acc[j].z += a * bv.z; acc[j].w += a * bv.w;
      }
    }
#pragma unroll
    for (int j = 0; j < 4; ++j) {
      int e = base + eg + j * 8;
      if (e < E) {
        ushort4 s;
        s.x = f2bf(acc[j].x); s.y = f2bf(acc[j].y);
        s.z = f2bf(acc[j].z); s.w = f2bf(acc[j].w);
        *reinterpret_cast<ushort4*>(UVp + (size_t)e * 128 + c0) = s;
      }
    }
  }

  if (accum_g) {
    red[t] = gsum;
    __syncthreads();
    if (t < 64) atomicAdd(&g[t], red[t] + red[t + 64] + red[t + 128] + red[t + 192]);
  }
}

// ---- FUSED PATH v2: wave-local pair-agg + register GEMM + UV-out ----
// All dependencies wave-private (wave wv owns rows wv*8..wv*8+8): no Ms LDS,
// no __syncthreads except the final g-reduction. LDS 17.6KB -> 24 waves/CU cap
// (vs 12 before). Round-12 profile: Occupancy 29%, VALUBusy 28% => latency-bound
// gather starved of MLP; this doubles wave count and gather ILP (8-wide unroll).
__global__ __launch_bounds__(256, 6) void k_fused(const unsigned short* __restrict__ UVin,
                                                  const int* __restrict__ offsets,
                                                  const int* __restrict__ sorted_first,
                                                  const float* __restrict__ h_in,
                                                  float* __restrict__ h_out,
                                                  const float* __restrict__ Wg,
                                                  const float* __restrict__ bg,
                                                  const float* __restrict__ Wuv,
                                                  const float* __restrict__ bmsg,
                                                  unsigned short* __restrict__ UVout,
                                                  float* __restrict__ g,
                                                  int E, int write_uv, int accum_g) {
  __shared__ float As[32 * 129];   // [agg | h]; wave-local row slices
  __shared__ float red[256];
  int t = threadIdx.x;
  int wv = t >> 6, c = t & 63;
  int base = blockIdx.x * 32;
  int r0 = wv * 8;

  // ---- phase 0: stage h rows (wave-local) -> As[row][64+c]
#pragma unroll
  for (int j = 0; j < 8; ++j) {
    int row = r0 + j;
    int e = base + row;
    float hv = (e < E) ? h_in[(size_t)e * 64 + c] : 0.f;
    As[row * 129 + 64 + c] = hv;
  }

  // ---- phase 1: pair aggregation (wave-local) -> As[row][c]
#pragma unroll 1
  for (int j = 0; j < 8; ++j) {
    int row = r0 + j;
    int e = base + row;
    float acc = 0.f;
    if (e < E) {
      float vb = bf2f(UVin[(size_t)e * 128 + 64 + c]);
      int i = __builtin_amdgcn_readfirstlane(offsets[e]);
      int end = __builtin_amdgcn_readfirstlane(offsets[e + 1]);
      for (; i + 7 < end; i += 8) {
        int f0 = __builtin_amdgcn_readfirstlane(sorted_first[i]);
        int f1 = __builtin_amdgcn_readfirstlane(sorted_first[i + 1]);
        int f2 = __builtin_amdgcn_readfirstlane(sorted_first[i + 2]);
        int f3 = __builtin_amdgcn_readfirstlane(sorted_first[i + 3]);
        int f4 = __builtin_amdgcn_readfirstlane(sorted_first[i + 4]);
        int f5 = __builtin_amdgcn_readfirstlane(sorted_first[i + 5]);
        int f6 = __builtin_amdgcn_readfirstlane(sorted_first[i + 6]);
        int f7 = __builtin_amdgcn_readfirstlane(sorted_first[i + 7]);
        float u0 = bf2f(UVin[(size_t)f0 * 128 + c]);
        float u1 = bf2f(UVin[(size_t)f1 * 128 + c]);
        float u2 = bf2f(UVin[(size_t)f2 * 128 + c]);
        float u3 = bf2f(UVin[(size_t)f3 * 128 + c]);
        float u4 = bf2f(UVin[(size_t)f4 * 128 + c]);
        float u5 = bf2f(UVin[(size_t)f5 * 128 + c]);
        float u6 = bf2f(UVin[(size_t)f6 * 128 + c]);
        float u7 = bf2f(UVin[(size_t)f7 * 128 + c]);
        acc += selu_f(u0 + vb); acc += selu_f(u1 + vb);
        acc += selu_f(u2 + vb); acc += selu_f(u3 + vb);
        acc += selu_f(u4 + vb); acc += selu_f(u5 + vb);
        acc += selu_f(u6 + vb); acc += selu_f(u7 + vb);
      }
      for (; i + 3 < end; i += 4) {
        int f0 = __builtin_amdgcn_readfirstlane(sorted_first[i]);
        int f1 = __builtin_amdgcn_readfirstlane(sorted_first[i + 1]);
        int f2 = __builtin_amdgcn_readfirstlane(sorted_first[i + 2]);
        int f3 = __builtin_amdgcn_readfirstlane(sorted_first[i + 3]);
        acc += selu_f(bf2f(UVin[(size_t)f0 * 128 + c]) + vb);
        acc += selu_f(bf2f(UVin[(size_t)f1 * 128 + c]) + vb);
        acc += selu_f(bf2f(UVin[(size_t)f2 * 128 + c]) + vb);
        acc += selu_f(bf2f(UVin[(size_t)f3 * 128 + c]) + vb);
      }
      for (; i < end; ++i) {
        int f0 = __builtin_amdgcn_readfirstlane(sorted_first[i]);
        acc += selu_f(bf2f(UVin[(size_t)f0 * 128 + c]) + vb);
      }
    }
    As[row * 129 + c] = acc;
  }
  // no barrier: GEMM below reads only this wave's As rows (lgkmcnt-ordered)

  // ---- phase 2: register GEMM. lane c accumulates cols {c,64+c,128+c,192+c}
  float mz[8], mr[8], mx2[8], mi2[8];
  {
    float bz = bg[c], br = bg[64 + c], bx = bg[128 + c], bi = bg[192 + c];
#pragma unroll
    for (int e2 = 0; e2 < 8; ++e2) { mz[e2] = bz; mr[e2] = br; mx2[e2] = bx; mi2[e2] = bi; }
  }
#pragma unroll 4
  for (int k = 0; k < 64; ++k) {      // A = agg slice
    float wz = Wg[k * 256 + c];
    float wr = Wg[k * 256 + 64 + c];
    float wx = Wg[k * 256 + 128 + c];
#pragma unroll
    for (int e2 = 0; e2 < 8; ++e2) {
      float a = As[(r0 + e2) * 129 + k];
      mz[e2] = fmaf(a, wz, mz[e2]);
      mr[e2] = fmaf(a, wr, mr[e2]);
      mx2[e2] = fmaf(a, wx, mx2[e2]);
    }
  }
#pragma unroll 4
  for (int k = 64; k < 128; ++k) {    // A = h slice
    float wz = Wg[k * 256 + c];
    float wr = Wg[k * 256 + 64 + c];
    float wi = Wg[k * 256 + 192 + c];
#pragma unroll
    for (int e2 = 0; e2 < 8; ++e2) {
      float a = As[(r0 + e2) * 129 + k];
      mz[e2] = fmaf(a, wz, mz[e2]);
      mr[e2] = fmaf(a, wr, mr[e2]);
      mi2[e2] = fmaf(a, wi, mi2[e2]);
    }
  }

  // ---- phase 3: gate epilogue; h_new -> global (skip last iter) + As h-slot
  float gsum = 0.f;
#pragma unroll
  for (int e2 = 0; e2 < 8; ++e2) {
    int row = r0 + e2;
    int ge = base + row;
    float hold = As[row * 129 + 64 + c];
    float z = sigm_f(mz[e2]);
    float r = sigm_f(mr[e2]);
    float hh = tanh_f(mx2[e2] + r * mi2[e2]);
    float hn = z * hold + (1.f - z) * hh;
    if (ge < E) {
      if (!accum_g) h_out[(size_t)ge * 64 + c] = hn;
    } else {
      hn = 0.f;
    }
    As[row * 129 + 64 + c] = hn;
    gsum += hn;
  }

  // ---- phase 4: UVout = [h_new @ W_top | h_new @ W_bot + bmsg] (wave-local)
  if (write_uv) {
    float au[8], av[8];
    float bm = bmsg[c];
#pragma unroll
    for (int e2 = 0; e2 < 8; ++e2) { au[e2] = 0.f; av[e2] = bm; }
#pragma unroll 4
    for (int k = 0; k < 64; ++k) {
      float wu = Wuv[k * 128 + c];
      float wv2 = Wuv[k * 128 + 64 + c];
#pragma unroll
      for (int e2 = 0; e2 < 8; ++e2) {
        float hv = As[(r0 + e2) * 129 + 64 + k];
        au[e2] = fmaf(hv, wu, au[e2]);
        av[e2] = fmaf(hv, wv2, av[e2]);
      }
    }
#pragma unroll
    for (int e2 = 0; e2 < 8; ++e2) {
      int e = base + r0 + e2;
      if (e < E) {
        UVout[(size_t)e * 128 + c] = f2bf(au[e2]);
        UVout[(size_t)e * 128 + 64 + c] = f2bf(av[e2]);
      }
    }
  }

  // ---- phase 5: readout column-sum (last iteration only)
  if (accum_g) {
    red[t] = gsum;
    __syncthreads();
    if (t < 64) atomicAdd(&g[t], red[t] + red[t + 64] + red[t + 128] + red[t + 192]);
  }
}

__global__ __launch_bounds__(256) void k_mlp(const float* __restrict__ g,
                                             const float* __restrict__ W1, const float* __restrict__ b1,
                                             const float* __restrict__ W2, const float* __restrict__ b2,
                                             const float* __restrict__ W3, const float* __restrict__ b3,
                                             float* __restrict__ out) {
  __shared__ float gs[64];
  __shared__ float h1[256];
  __shared__ float h2[256];
  __shared__ float red[256];
  int t = threadIdx.x;
  if (t < 64) gs[t] = g[t];
  __syncthreads();
  float acc = b1[t];
#pragma unroll
  for (int k = 0; k < 64; ++k) acc += gs[k] * W1[k * 256 + t];
  h1[t] = selu_f(acc);
  __syncthreads();
  acc = b2[t];
#pragma unroll 8
  for (int k = 0; k < 256; ++k) acc += h1[k] * W2[k * 256 + t];
  h2[t] = selu_f(acc);
  __syncthreads();
  red[t] = h2[t] * W3[t];
  __syncthreads();
  for (int d = 128; d > 0; d >>= 1) {
    if (t < d) red[t] += red[t + d];
    __syncthreads();
  }
  if (t == 0) out[0] = red[0] + b3[0];
}

extern "C" void kernel_launch(void* const* d_in, const int* in_sizes, int n_in,
                              void* d_out, int out_size, void* d_ws, size_t ws_size,
                              hipStream_t stream) {
  const float* ls   = (const float*)d_in[0];
  const int*   fst  = (const int*)d_in[1];
  const int*   sec  = (const int*)d_in[2];
  const float* Wmsg = (const float*)d_in[4];
  const float* bmsg = (const float*)d_in[5];
  const float* gk   = (const float*)d_in[6];
  const float* grk  = (const float*)d_in[7];
  const float* gb   = (const float*)d_in[8];
  const float* W1   = (const float*)d_in[9];
  const float* b1   = (const float*)d_in[10];
  const float* W2   = (const float*)d_in[11];
  const float* b2   = (const float*)d_in[12];
  const float* W3   = (const float*)d_in[13];
  const float* b3   = (const float*)d_in[14];
  int E = in_sizes[0] / D;
  int P = in_sizes[1];
  float* out = (float*)d_out;
  (void)n_in; (void)out_size;

  int NB = (E + 1023) / 1024;  // scan blocks (E=100K -> 98, must be <=1024)

  // ws layout (graph-safe: depends only on ws_size):
  //  fused:    h + 2x bf16 UV (ping-pong)           ~84.2 MB
  //  fallback: h + 1x bf16 UV + bf16 agg (separate) ~71.4 MB
  auto total_need = [&](int fused) -> size_t {
    size_t o = 0;
    auto add = [&](size_t b) { o = (o + b + 255) & ~(size_t)255; };
    add((size_t)E * 64 * 4);                      // h
    add((size_t)E * 128 * 2);                     // UV0 bf16
    add(fused ? (size_t)E * 128 * 2              // UV1 bf16 (ping-pong)
              : (size_t)E * 64 * 2);             // agg bf16
    add(((size_t)E + 1) * 4);                     // offsets
    add((size_t)E * 4);                           // counts (aliased by cursor)
    add((size_t)NB * 4);                          // bsums
    add((size_t)P * 4);                           // sorted_first
    add(64 * 128 * 4);                            // Wuv
    add(128 * 256 * 4);                           // Wg
    add(256 * 4);                                 // bg
    add(64 * 4);                                  // g
    return o;
  };
  int fused = (total_need(1) <= ws_size) ? 1 : 0;

  char* ws = (char*)d_ws;
  size_t off = 0;
  auto alloc = [&](size_t bytes) {
    void* p = ws + off;
    off = (off + bytes + 255) & ~(size_t)255;
    return p;
  };
  float*          h     = (float*)alloc((size_t)E * 64 * 4);
  unsigned short* UV0   = (unsigned short*)alloc((size_t)E * 128 * 2);
  unsigned short* UV1   = nullptr;   // fused only
  unsigned short* aggb  = nullptr;   // fallback only
  if (fused) UV1  = (unsigned short*)alloc((size_t)E * 128 * 2);
  else       aggb = (unsigned short*)alloc((size_t)E * 64 * 2);
  int*   offsets      = (int*)alloc(((size_t)E + 1) * 4);
  int*   counts       = (int*)alloc((size_t)E * 4);
  int*   cursor       = counts;  // alias: scan3 reads-then-writes each slot in-thread
  int*   bsums        = (int*)alloc((size_t)NB * 4);
  int*   sorted_first = (int*)alloc((size_t)P * 4);
  float* Wuv          = (float*)alloc(64 * 128 * 4);
  float* Wg           = (float*)alloc(128 * 256 * 4);
  float* bg           = (float*)alloc(256 * 4);
  float* g            = (float*)alloc(64 * 4);

  hipMemsetAsync(counts, 0, (size_t)E * 4, stream);
  hipMemsetAsync(g, 0, 64 * 4, stream);
  k_hist<<<(P + 255) / 256, 256, 0, stream>>>(sec, counts, P);
  k_scan1<<<NB, 256, 0, stream>>>(counts, bsums, E);
  k_scan2<<<1, 1024, 0, stream>>>(bsums, NB);
  k_scan3<<<NB, 256, 0, stream>>>(counts, bsums, offsets, cursor, E, P);
  k_scatter<<<(P + 255) / 256, 256, 0, stream>>>(fst, sec, cursor, sorted_first, P);
  k_prep<<<128, 256, 0, stream>>>(Wmsg, gk, grk, gb, Wuv, Wg, bg);

  int gemm_blocks = (E + 31) / 32;
  int pair_blocks = (E + 3) / 4;

  k_uv<<<gemm_blocks, 256, 0, stream>>>(ls, Wuv, bmsg, UV0, E);
  if (fused) {
    unsigned short* UVa = UV0;
    unsigned short* UVb = UV1;
    for (int it = 0; it < TSTEPS; ++it) {
      const float* hin = (it == 0) ? ls : h;
      int last = (it == TSTEPS - 1);
      k_fused<<<gemm_blocks, 256, 0, stream>>>(UVa, offsets, sorted_first, hin, h,
                                               Wg, bg, Wuv, bmsg, UVb, g,
                                               E, !last, last);
      unsigned short* tmp = UVa; UVa = UVb; UVb = tmp;
    }
  } else {
    for (int it = 0; it < TSTEPS; ++it) {
      const float* hin = (it == 0) ? ls : h;
      int last = (it == TSTEPS - 1);
      k_pair<<<pair_blocks, 256, 0, stream>>>(UV0, offsets, sorted_first, aggb, E);
      k_gru<<<gemm_blocks, 256, 0, stream>>>(aggb, hin, h, Wg, bg, Wuv, bmsg, UV0, g,
                                             E, !last, last);
    }
  }
  k_mlp<<<1, 256, 0, stream>>>(g, W1, b1, W2, b2, W3, b3, out);
}